// Round 8
// baseline (230.667 us; speedup 1.0000x reference)
//
#include <hip/hip_runtime.h>
#include <hip/hip_bf16.h>
#include <math.h>

#define BB 2
#define NN 8192
#define DD 512
#define HH 8
#define DK 64
#define KNB 32
#define BN (BB*NN)          // 16384 rows
#define BHN (BB*HH*NN)      // 131072 (b,h,n) tuples

typedef __attribute__((ext_vector_type(8))) _Float16 f16x8;   // 8 f16 in 4 VGPRs
typedef __attribute__((ext_vector_type(2))) _Float16 f16x2;
typedef __attribute__((ext_vector_type(4))) float f32x4;

#if __has_builtin(__builtin_amdgcn_fdot2)
#define HAS_FDOT2 1
#endif

__device__ __forceinline__ unsigned short f2h(float f) {
    return __builtin_bit_cast(unsigned short, (_Float16)f);
}
__device__ __forceinline__ f16x2 u2h2(unsigned u) {
    return __builtin_bit_cast(f16x2, u);
}
__device__ __forceinline__ float h2f_lo(unsigned u) {
    return (float)__builtin_bit_cast(_Float16, (unsigned short)(u & 0xffffu));
}
__device__ __forceinline__ float h2f_hi(unsigned u) {
    return (float)__builtin_bit_cast(_Float16, (unsigned short)(u >> 16));
}
// dot of packed f16 pairs with fp32 accumulate
__device__ __forceinline__ float dot2h(unsigned a, unsigned b, float c) {
#ifdef HAS_FDOT2
    return __builtin_amdgcn_fdot2(u2h2(a), u2h2(b), c, false);
#else
    c = fmaf(h2f_lo(a), h2f_lo(b), c);
    return fmaf(h2f_hi(a), h2f_hi(b), c);
#endif
}

// async global->LDS DMA. LDS dest is wave-uniform base; HW adds lane*width.
__device__ __forceinline__ void gload_lds16(const void* gptr, void* lptr) {
    __builtin_amdgcn_global_load_lds(
        (const __attribute__((address_space(1))) unsigned int*)gptr,
        (__attribute__((address_space(3))) unsigned int*)lptr,
        16, 0, 0);
}
__device__ __forceinline__ void gload_lds4(const void* gptr, void* lptr) {
    __builtin_amdgcn_global_load_lds(
        (const __attribute__((address_space(1))) unsigned int*)gptr,
        (__attribute__((address_space(3))) unsigned int*)lptr,
        4, 0, 0);
}

// ---------------- fp32 -> f16 converter (x + all weights, one launch) ----------------
__global__ __launch_bounds__(256) void cvt_all(
    const float* __restrict__ x,
    const float* __restrict__ Wq, const float* __restrict__ Wk,
    const float* __restrict__ Wv, const float* __restrict__ Wo,
    unsigned short* __restrict__ Xb, unsigned short* __restrict__ Wfb,
    unsigned short* __restrict__ Wob)
{
    const int blk = blockIdx.x;
    const float* src;
    unsigned short* dst;
    int off;
    if (blk < 8192) {
        off = (blk * 256 + threadIdx.x) * 4;
        src = x; dst = Xb;
    } else {
        const int e = ((blk - 8192) * 256 + threadIdx.x) * 4;   // over 4*262144
        const int t = e >> 18;
        off = e & 262143;
        src = (t == 0) ? Wq : (t == 1) ? Wk : (t == 2) ? Wv : Wo;
        dst = (t < 3) ? (Wfb + (size_t)t * 262144) : Wob;
    }
    const float4 v = *(const float4*)(src + off);
    ushort4 u;
    u.x = f2h(v.x); u.y = f2h(v.y); u.z = f2h(v.z); u.w = f2h(v.w);
    *(ushort4*)(dst + off) = u;
}

// ---------------- Kernel 1: fused QKV projection + LayerNorm, f16 MFMA ----------------
// M=16384, N=1536 (Q|K|V), K=512. 128x128 tile, BK=64 staged as TWO proven
// BK=32 sub-tiles per barrier pair (single 128B-row tile would 16-way bank
// conflict; padding breaks global_load_lds) -> 8 K-iters, 32 MFMA/barrier.
// 1D grid with XCD swizzle: xcd=p&7 owns rows [xcd*16,+16) x all 12 cols, so
// its A-slice (2 MB) + all W (1.5 MB) stay resident in that XCD's 4 MB L2.
__global__ __launch_bounds__(256) void gemm_qkv(
    const unsigned short* __restrict__ Xb, const unsigned short* __restrict__ Wfb,
    unsigned short* __restrict__ Qh, unsigned short* __restrict__ Kh,
    unsigned short* __restrict__ Vh)
{
    __shared__ unsigned short Als[2][128 * 32];   // 2 x 8 KB
    __shared__ unsigned short Bls[2][128 * 32];   // 2 x 8 KB
    const int tid  = threadIdx.x;
    const int wave = tid >> 6, lane = tid & 63;
    const int wm = wave >> 1, wn = wave & 1;
    const int quad = lane >> 4, r = lane & 15;
    const int p = blockIdx.x;                     // 0..1535
    const int xcd = p & 7, within = p >> 3;       // within: 0..191
    const int row0 = (xcd * 16 + (within & 15)) * 128;
    const int c0   = (within >> 4) * 128;         // col tile 0..11

    f32x4 acc[4][4];
    #pragma unroll
    for (int i = 0; i < 4; ++i)
        #pragma unroll
        for (int j = 0; j < 4; ++j) acc[i][j] = (f32x4)0.f;

    const char* Ab = (const char*)Xb;
    const char* Bb = (const char*)Wfb;

    for (int k0 = 0; k0 < 512; k0 += 64) {
        __syncthreads();
        #pragma unroll
        for (int s = 0; s < 2; ++s) {
            #pragma unroll
            for (int q = 0; q < 2; ++q) {
                const int li = q * 4096 + wave * 1024 + lane * 16;  // byte in 8 KB sub-tile
                const int rr = li >> 6, off = li & 63;              // 64 B per 32-f16 row
                gload_lds16(Ab + (size_t)(row0 + rr) * 1024 + (k0 + s * 32) * 2 + off,
                            (char*)Als[s] + (q * 4096 + wave * 1024));
                gload_lds16(Bb + (size_t)(c0 + rr) * 1024 + (k0 + s * 32) * 2 + off,
                            (char*)Bls[s] + (q * 4096 + wave * 1024));
            }
        }
        __syncthreads();

        #pragma unroll
        for (int s = 0; s < 2; ++s) {
            f16x8 af[4], bf[4];
            #pragma unroll
            for (int i = 0; i < 4; ++i)
                af[i] = *(const f16x8*)(&Als[s][(wm * 64 + i * 16 + r) * 32 + quad * 8]);
            #pragma unroll
            for (int j = 0; j < 4; ++j)
                bf[j] = *(const f16x8*)(&Bls[s][(wn * 64 + j * 16 + r) * 32 + quad * 8]);
            #pragma unroll
            for (int i = 0; i < 4; ++i)
                #pragma unroll
                for (int j = 0; j < 4; ++j)
                    acc[i][j] = __builtin_amdgcn_mfma_f32_16x16x32_f16(af[i], bf[j], acc[i][j], 0, 0, 0);
        }
    }

    const int tensor = c0 >> 9;   // block-uniform: 0=Q 1=K 2=V
    unsigned short* OutH = (tensor == 0) ? Qh : (tensor == 1) ? Kh : Vh;

    float mu[4][4], rs[4][4];
    if (tensor < 2) {
        #pragma unroll
        for (int i = 0; i < 4; ++i) {
            #pragma unroll
            for (int reg = 0; reg < 4; ++reg) {
                float sm = acc[i][0][reg] + acc[i][1][reg] + acc[i][2][reg] + acc[i][3][reg];
                sm += __shfl_xor(sm, 1); sm += __shfl_xor(sm, 2);
                sm += __shfl_xor(sm, 4); sm += __shfl_xor(sm, 8);
                const float muv = sm * (1.f / 64.f);
                float qv = 0.f;
                #pragma unroll
                for (int j = 0; j < 4; ++j) {
                    const float dv = acc[i][j][reg] - muv;
                    qv = fmaf(dv, dv, qv);
                }
                qv += __shfl_xor(qv, 1); qv += __shfl_xor(qv, 2);
                qv += __shfl_xor(qv, 4); qv += __shfl_xor(qv, 8);
                mu[i][reg] = muv;
                rs[i][reg] = rsqrtf(qv * (1.f / 64.f) + 1e-5f);
            }
        }
    }

    // C/D layout col=lane&15, row=quad*4+reg (verified m89).
    #pragma unroll
    for (int i = 0; i < 4; ++i) {
        #pragma unroll
        for (int j = 0; j < 4; ++j) {
            const int cc = (c0 & 511) + wn * 64 + j * 16 + r;
            const int h = cc >> 6, d = cc & 63;
            #pragma unroll
            for (int reg = 0; reg < 4; ++reg) {
                const int row = row0 + wm * 64 + i * 16 + quad * 4 + reg;
                const int b = row >> 13, n = row & 8191;
                float v = acc[i][j][reg];
                if (tensor < 2) v = (v - mu[i][reg]) * rs[i][reg];
                OutH[(((size_t)(b * HH + h) * NN + n) << 6) + d] = f2h(v);
            }
        }
    }
}

// ---------------- Kernel 2: gather-attention with async V staging ----------------
// (unchanged from round 7: LDS DMA staging of the 32 gathered V rows overlapped
// by the score phase; VALUBusy 78% -> near issue-bound at 84.5 us)
__global__ __launch_bounds__(256, 2) void attn(
    const unsigned short* __restrict__ Qh, const unsigned short* __restrict__ Kh,
    const unsigned short* __restrict__ Vh,
    const int* __restrict__ idx, unsigned short* __restrict__ Ob)
{
    __shared__ unsigned short Vls[4][2048];         // per-wave 32 rows x 128 B
    const int p = blockIdx.x;                       // 0..32767
    const int L = ((p & 7) << 12) | (p >> 3);       // XCD-contiguous logical id
    const int wave = threadIdx.x >> 6;
    const int wid  = L * 4 + wave;                  // 0..BHN-1
    const int lane = threadIdx.x & 63;
    const int bh = wid >> 13;
    const int n  = wid & 8191;
    const size_t base = (size_t)bh * NN * DK;       // element offset of (b,h) slab

    const int k    = lane >> 1;
    const int half = lane & 1;
    const int g    = idx[n * KNB + k];              // pair-duplicated

    const unsigned gg = (unsigned)g | (((unsigned)__shfl_xor(g, 2)) << 16);

    // Phase 1: stage all 32 V rows into LDS (async DMA, no dest VGPRs).
    char* lw = (char*)Vls[wave];
    const char* Vbytes = (const char*)Vh + (base << 1);
    const int col4 = (lane & 31) * 4;
    const int sub  = lane >> 5;
    #pragma unroll
    for (int j = 0; j < 16; ++j) {
        const unsigned gpair = (unsigned)__builtin_amdgcn_readlane((int)gg, j * 4);
        const int grow = sub ? (int)(gpair >> 16) : (int)(gpair & 0xffffu);
        gload_lds4(Vbytes + grow * 128 + col4, lw + j * 256);
    }

    // Phase 2: score. Half-row dot: 32 elements each, as 16 packed f16 pairs.
    const uint4* q4 = (const uint4*)(Qh + base + ((size_t)n << 6) + half * 32);
    const uint4* k4 = (const uint4*)(Kh + base + ((size_t)g << 6) + half * 32);
    float acc = 0.f;
    #pragma unroll
    for (int c = 0; c < 4; ++c) {
        const uint4 qa = q4[c], ka = k4[c];
        acc = dot2h(qa.x, ka.x, acc);
        acc = dot2h(qa.y, ka.y, acc);
        acc = dot2h(qa.z, ka.z, acc);
        acc = dot2h(qa.w, ka.w, acc);
    }
    float s = (acc + __shfl_xor(acc, 1)) * 0.125f;  // 1/sqrt(64)

    float m = s;
    #pragma unroll
    for (int off = 2; off <= 32; off <<= 1) m = fmaxf(m, __shfl_xor(m, off));
    const float e = __expf(s - m);
    float tot = e;
    #pragma unroll
    for (int off = 2; off <= 32; off <<= 1) tot += __shfl_xor(tot, off);
    const float pr = e / tot;

    const unsigned prh = (unsigned)f2h(pr);
    const unsigned pp = prh | (((unsigned)__shfl_xor((int)prh, 2)) << 16);

    // Phase 3: DMA visible after the barrier (vmcnt drained), then LDS chain.
    __syncthreads();
    const unsigned short* lv = (const unsigned short*)Vls[wave];
    float o = 0.f;
    #pragma unroll
    for (int j = 0; j < 16; ++j) {
        const unsigned ppair = (unsigned)__builtin_amdgcn_readlane((int)pp, j * 4);
        const unsigned v0 = lv[j * 128 + lane];         // row 2j,  dim=lane
        const unsigned v1 = lv[j * 128 + 64 + lane];    // row 2j+1, dim=lane
        o = dot2h(v0 | (v1 << 16), ppair, o);
    }
    const int b = bh >> 3, h = bh & 7;
    Ob[((size_t)(b * NN + n)) * DD + h * DK + lane] = f2h(o);
}

// ---------------- Kernel 3: output projection, f16 MFMA ----------------
// Same BK=64 double-sub-tile + XCD swizzle. M=16384, N=512, K=512.
__global__ __launch_bounds__(256) void gemm_out(
    const unsigned short* __restrict__ Ob, const unsigned short* __restrict__ Wob,
    const float* __restrict__ bout, float* __restrict__ out)
{
    __shared__ unsigned short Als[2][128 * 32];
    __shared__ unsigned short Bls[2][128 * 32];
    const int tid  = threadIdx.x;
    const int wave = tid >> 6, lane = tid & 63;
    const int wm = wave >> 1, wn = wave & 1;
    const int quad = lane >> 4, r = lane & 15;
    const int p = blockIdx.x;                     // 0..511
    const int xcd = p & 7, within = p >> 3;       // within: 0..63
    const int row0 = (xcd * 16 + (within & 15)) * 128;
    const int c0   = (within >> 4) * 128;         // col tile 0..3

    f32x4 acc[4][4];
    #pragma unroll
    for (int i = 0; i < 4; ++i)
        #pragma unroll
        for (int j = 0; j < 4; ++j) acc[i][j] = (f32x4)0.f;

    const char* Ab = (const char*)Ob;
    const char* Bb = (const char*)Wob;

    for (int k0 = 0; k0 < 512; k0 += 64) {
        __syncthreads();
        #pragma unroll
        for (int s = 0; s < 2; ++s) {
            #pragma unroll
            for (int q = 0; q < 2; ++q) {
                const int li = q * 4096 + wave * 1024 + lane * 16;
                const int rr = li >> 6, off = li & 63;
                gload_lds16(Ab + (size_t)(row0 + rr) * 1024 + (k0 + s * 32) * 2 + off,
                            (char*)Als[s] + (q * 4096 + wave * 1024));
                gload_lds16(Bb + (size_t)(c0 + rr) * 1024 + (k0 + s * 32) * 2 + off,
                            (char*)Bls[s] + (q * 4096 + wave * 1024));
            }
        }
        __syncthreads();

        #pragma unroll
        for (int s = 0; s < 2; ++s) {
            f16x8 af[4], bf[4];
            #pragma unroll
            for (int i = 0; i < 4; ++i)
                af[i] = *(const f16x8*)(&Als[s][(wm * 64 + i * 16 + r) * 32 + quad * 8]);
            #pragma unroll
            for (int j = 0; j < 4; ++j)
                bf[j] = *(const f16x8*)(&Bls[s][(wn * 64 + j * 16 + r) * 32 + quad * 8]);
            #pragma unroll
            for (int i = 0; i < 4; ++i)
                #pragma unroll
                for (int j = 0; j < 4; ++j)
                    acc[i][j] = __builtin_amdgcn_mfma_f32_16x16x32_f16(af[i], bf[j], acc[i][j], 0, 0, 0);
        }
    }

    #pragma unroll
    for (int i = 0; i < 4; ++i) {
        #pragma unroll
        for (int j = 0; j < 4; ++j) {
            const int colg = c0 + wn * 64 + j * 16 + r;
            const float bb = bout[colg];
            #pragma unroll
            for (int reg = 0; reg < 4; ++reg) {
                const int row = row0 + wm * 64 + i * 16 + quad * 4 + reg;
                out[((size_t)row << 9) + colg] = acc[i][j][reg] + bb;
            }
        }
    }
}

extern "C" void kernel_launch(void* const* d_in, const int* in_sizes, int n_in,
                              void* d_out, int out_size, void* d_ws, size_t ws_size,
                              hipStream_t stream)
{
    const float* x    = (const float*)d_in[0];
    const int*   idx  = (const int*)  d_in[1];
    const float* Wq   = (const float*)d_in[2];
    const float* Wk   = (const float*)d_in[3];
    const float* Wv   = (const float*)d_in[4];
    const float* Wout = (const float*)d_in[5];
    const float* bout = (const float*)d_in[6];

    char* ws = (char*)d_ws;
    unsigned short* Qh  = (unsigned short*)(ws);              // 16777216 B
    unsigned short* Kh  = (unsigned short*)(ws + 16777216);   // 16777216 B
    unsigned short* Vh  = (unsigned short*)(ws + 33554432);   // 16777216 B
    unsigned short* Xb  = (unsigned short*)(ws + 50331648);   // 16777216 B; aliased as Ob
    unsigned short* Ob  = Xb;
    unsigned short* Wfb = (unsigned short*)(ws + 67108864);   // 1572864 B (Wq|Wk|Wv rows)
    unsigned short* Wob = (unsigned short*)(ws + 68681728);   // 524288 B
    float* out = (float*)d_out;

    cvt_all<<<9216, 256, 0, stream>>>(x, Wq, Wk, Wv, Wout, Xb, Wfb, Wob);

    gemm_qkv<<<1536, 256, 0, stream>>>(Xb, Wfb, Qh, Kh, Vh);

    attn<<<BHN / 4, 256, 0, stream>>>(Qh, Kh, Vh, idx, Ob);

    gemm_out<<<512, 256, 0, stream>>>(Ob, Wob, bout, out);
}